// Round 5
// baseline (694.971 us; speedup 1.0000x reference)
//
#include <hip/hip_runtime.h>
#include <hip/hip_bf16.h>

// TAGConv K=2, D=128. Round 12.
// Evidence: spmm = 62.9us x2 is the miss-path floor (213MB @ 3.4TB/s random
// 256B granules; MLP ample at 22 waves/CU). Cross-round differencing shows
// rocprof durations track wall time 1:1 -> gaps = 301 - (125 spmm + ~60
// mega/csr/gemm/memset) ~= 110us over 6 graph nodes (~19us each). Round-1's
// fusion failed only because cg::grid.sync() costs ~120-190us at 2048 blocks.
// This round: fuse {mega, csr, spmm1, spmm2} in ONE cooperative kernel with a
// HAND-ROLLED two-level barrier (8 cacheline-spread group counters -> root ->
// release word; monotonic thresholds, no resets; agent-scope fences for
// cross-XCD visibility; s_sleep spin). gemm stays separate (VGPR isolation)
// + nontemporal C stores. Fallback to the 6-dispatch pipeline on launch error.
// Pipeline: memset(2.3KB) -> fused(coop, 3 barriers) -> gemm.

#define D 128
#define TPB 256              // fallback spmm / gemm block
#define TPB_F 512            // fused kernel block (8 waves)
#define GEMM_GRID 768

#define BSH 9
#define BSZ 512              // nodes per bucket
#define NBMAX 256            // max buckets
#define EPT 8                // edges per thread in binscatter
#define CH (TPB_F * EPT)     // 4096 edges per chunk
#define LCAP 16384           // fixed per-bucket region (avg fill ~8.2K)

#define NGRP 8
#define BAR_INTS (NGRP * 32 + 64)   // 8 spread group counters + root + gen

typedef __attribute__((ext_vector_type(8))) short short8;
typedef __attribute__((ext_vector_type(4))) float f32x4;

__device__ __forceinline__ ushort f2bf(float f) {
    unsigned u = __float_as_uint(f);
    u += 0x7fff + ((u >> 16) & 1);      // round-to-nearest-even
    return (ushort)(u >> 16);
}
__device__ __forceinline__ unsigned pack2bf(float x, float y) {
    return (unsigned)f2bf(x) | ((unsigned)f2bf(y) << 16);
}
__device__ __forceinline__ float bf_lo(unsigned v) { return __uint_as_float(v << 16); }
__device__ __forceinline__ float bf_hi(unsigned v) { return __uint_as_float(v & 0xffff0000u); }

// ---------------- two-level grid barrier (hand-rolled) ----------------
// bar[g*32]: group-g arrival counter (one cache line each); bar[NGRP*32]:
// root counter; bar[NGRP*32+32]: release generation. All zeroed by the
// host memset each launch; barrier k uses monotonic threshold (k+1)*count
// so counters never reset. Agent-scope fences give cross-XCD visibility.
__device__ __forceinline__ void gridbar(int* bar, int k, int nblk) {
    __syncthreads();
    if (threadIdx.x == 0) {
        int grp = (int)(blockIdx.x & (NGRP - 1));
        int nbg = (nblk - grp + NGRP - 1) / NGRP;   // blocks in this group
        __threadfence();                             // release my XCD's writes
        int a = __hip_atomic_fetch_add(&bar[grp * 32], 1, __ATOMIC_ACQ_REL,
                                       __HIP_MEMORY_SCOPE_AGENT);
        if (a == nbg * (k + 1) - 1) {                // last of group
            int r = __hip_atomic_fetch_add(&bar[NGRP * 32], 1, __ATOMIC_ACQ_REL,
                                           __HIP_MEMORY_SCOPE_AGENT);
            if (r == NGRP * (k + 1) - 1)             // last group overall
                __hip_atomic_store(&bar[NGRP * 32 + 32], k + 1, __ATOMIC_RELEASE,
                                   __HIP_MEMORY_SCOPE_AGENT);
        }
        while (__hip_atomic_load(&bar[NGRP * 32 + 32], __ATOMIC_ACQUIRE,
                                 __HIP_MEMORY_SCOPE_AGENT) < k + 1)
            __builtin_amdgcn_s_sleep(8);
        __threadfence();                             // acquire: invalidate stale
    }
    __syncthreads();
}

// ---------------- phase bodies (512-thread versions) ----------------

// mega: binscatter || prescale || wconv, selected by chunk id.
__device__ __forceinline__ void mega_body(
    int bid, int t,
    const int* __restrict__ src, const int* __restrict__ dst,
    int* __restrict__ gCursor, unsigned* __restrict__ tmp,
    const float* __restrict__ feat, unsigned* __restrict__ featb,
    const float* __restrict__ W, ushort* __restrict__ Wb,
    int e, int n, int nbin, int npre) {
    __shared__ int hist[NBMAX];
    __shared__ int cellBase[NBMAX];
    if (bid < nbin) {
        if (t < NBMAX) hist[t] = 0;
        __syncthreads();
        int base = bid * CH;
        int b[EPT]; unsigned pk[EPT]; int r[EPT];
#pragma unroll
        for (int k = 0; k < EPT; ++k) {
            int i = base + k * TPB_F + t;
            b[k] = -1;
            if (i < e) {
                int d = dst[i];
                b[k] = d >> BSH;
                pk[k] = ((unsigned)src[i] << BSH) | (unsigned)(d & (BSZ - 1));
                r[k] = atomicAdd(&hist[b[k]], 1);
            }
        }
        __syncthreads();
        if (t < NBMAX) {
            int h = hist[t];
            cellBase[t] = h ? t * LCAP + atomicAdd(&gCursor[t], h) : 0;
        }
        __syncthreads();
#pragma unroll
        for (int k = 0; k < EPT; ++k)
            if (b[k] >= 0) tmp[cellBase[b[k]] + r[k]] = pk[k];
        __syncthreads();            // LDS reuse guard (grid-stride loop)
    } else if (bid < nbin + npre) {
        int gid = (bid - nbin) * TPB_F + t;
        int node = gid >> 6, c = gid & 63;
        if (node < n) {
            float2 f = ((const float2*)(feat + (size_t)node * D))[c];
            featb[(size_t)node * 64 + c] = pack2bf(f.x, f.y);
        }
    } else {
        int i = ((bid - nbin - npre) * TPB_F + t) * 4;   // D*384 = 49152 elems
        float4 w = *(const float4*)(W + i);
        ushort4 o;
        o.x = f2bf(w.x); o.y = f2bf(w.y); o.z = f2bf(w.z); o.w = f2bf(w.w);
        *(ushort4*)(Wb + i) = o;
    }
}

// per-bucket CSR: LDS histogram + 512-thread scan, direct global scatter
// (no 64KB lcsr -> fused kernel keeps 4 blocks/CU). csr region is L2-hot.
__device__ __forceinline__ void bucket_body(
    int bkt, int t,
    const unsigned* __restrict__ tmp, const int* __restrict__ gCursor,
    int2* __restrict__ rsdeg, float* __restrict__ norm, int* __restrict__ csr,
    int n) {
    __shared__ int cnt[BSZ];
    __shared__ int off[BSZ];
    __shared__ int pr[BSZ];
    int beg = bkt * LCAP;
    int m = gCursor[bkt];
    int end = beg + m;
    cnt[t] = 0;
    __syncthreads();
    for (int i = beg + t; i < end; i += TPB_F)
        atomicAdd(&cnt[tmp[i] & (BSZ - 1)], 1);
    __syncthreads();
    int own = cnt[t];
    pr[t] = own;
    __syncthreads();
    for (int o = 1; o < BSZ; o <<= 1) {
        int x = (t >= o) ? pr[t - o] : 0;
        __syncthreads();
        pr[t] += x;
        __syncthreads();
    }
    off[t] = pr[t] - own;
    __syncthreads();
    cnt[t] = 0;                            // reuse as rank counters
    __syncthreads();
    for (int i = beg + t; i < end; i += TPB_F) {
        unsigned v = tmp[i];
        int l = v & (BSZ - 1);
        int r = atomicAdd(&cnt[l], 1);
        int idx = off[l] + r;
        if (idx < LCAP) csr[beg + idx] = (int)(v >> BSH);
    }
    __syncthreads();
    int node0 = bkt << BSH;
    {
        int node = node0 + t;
        if (node < n) {
            rsdeg[node] = make_int2(beg + off[t], cnt[t]);
            norm[node] = rsqrtf((float)cnt[t]);
        }
    }
    __syncthreads();                       // LDS reuse guard
}

// SpMM: hout[v] = bf16( norm[v] * sum_u norm[u]*hin[u] ); one wave per node,
// grid-stride; quarter-wave q handles edge beg+j*4+q; c=lane&15 -> 16B chunk.
__device__ __forceinline__ void spmm_body(
    const uint4* __restrict__ hin4, const int2* __restrict__ rsdeg,
    const int* __restrict__ csr, const float* __restrict__ norm,
    unsigned* __restrict__ hout, int n, int tpb) {
    int gw = (int)((blockIdx.x * tpb + threadIdx.x) >> 6);
    int nw = (int)((gridDim.x * tpb) >> 6);
    int lane = threadIdx.x & 63;
    int q = lane >> 4;
    int c = lane & 15;
    for (int w = gw; w < n; w += nw) {
        int2 rd = rsdeg[w];
        int beg = rd.x, end = rd.x + rd.y;
        float acc[8] = {};
#pragma unroll 4
        for (int j = beg + q; j < end; j += 4) {
            int u = csr[j];
            float s = norm[u];
            uint4 v = hin4[(u << 4) + c];
            acc[0] = fmaf(s, bf_lo(v.x), acc[0]);
            acc[1] = fmaf(s, bf_hi(v.x), acc[1]);
            acc[2] = fmaf(s, bf_lo(v.y), acc[2]);
            acc[3] = fmaf(s, bf_hi(v.y), acc[3]);
            acc[4] = fmaf(s, bf_lo(v.z), acc[4]);
            acc[5] = fmaf(s, bf_hi(v.z), acc[5]);
            acc[6] = fmaf(s, bf_lo(v.w), acc[6]);
            acc[7] = fmaf(s, bf_hi(v.w), acc[7]);
        }
#pragma unroll
        for (int k = 0; k < 8; ++k) {
            acc[k] += __shfl_xor(acc[k], 16, 64);
            acc[k] += __shfl_xor(acc[k], 32, 64);
        }
        if (q == 0) {
            float nv = norm[w];
            uint4 r;
            r.x = pack2bf(acc[0] * nv, acc[1] * nv);
            r.y = pack2bf(acc[2] * nv, acc[3] * nv);
            r.z = pack2bf(acc[4] * nv, acc[5] * nv);
            r.w = pack2bf(acc[6] * nv, acc[7] * nv);
            *(uint4*)(hout + (size_t)w * 64 + c * 4) = r;
        }
    }
}

// ---------------- fused cooperative kernel (hand barrier) ----------------
__global__ __launch_bounds__(TPB_F, 8) void fused_kernel(
    const int* __restrict__ src, const int* __restrict__ dst,
    int* __restrict__ gCursor, int* __restrict__ bar, unsigned* __restrict__ tmp,
    const float* __restrict__ feat, unsigned* __restrict__ featb,
    const float* __restrict__ W, ushort* __restrict__ Wb,
    int2* __restrict__ rsdeg, float* __restrict__ norm, int* __restrict__ csr,
    unsigned* __restrict__ h1b, unsigned* __restrict__ h2b,
    int e, int n, int nbin, int npre, int total1, int nb, int nblk) {
    int t = threadIdx.x;

    // phase 1: binscatter || prescale || wconv (gCursor pre-zeroed by memset)
    for (int bid = blockIdx.x; bid < total1; bid += gridDim.x)
        mega_body(bid, t, src, dst, gCursor, tmp, feat, featb, W, Wb,
                  e, n, nbin, npre);
    gridbar(bar, 0, nblk);

    // phase 2: per-bucket CSR
    for (int bkt = blockIdx.x; bkt < nb; bkt += gridDim.x)
        bucket_body(bkt, t, tmp, gCursor, rsdeg, norm, csr, n);
    gridbar(bar, 1, nblk);

    // phase 3: hop 1
    spmm_body((const uint4*)featb, rsdeg, csr, norm, h1b, n, TPB_F);
    gridbar(bar, 2, nblk);

    // phase 4: hop 2
    spmm_body((const uint4*)h1b, rsdeg, csr, norm, h2b, n, TPB_F);
}

// ---------------- fallback wrappers (non-cooperative path) ----------------
__global__ __launch_bounds__(TPB_F) void mega_kernel(
    const int* __restrict__ src, const int* __restrict__ dst,
    int* __restrict__ gCursor, unsigned* __restrict__ tmp,
    const float* __restrict__ feat, unsigned* __restrict__ featb,
    const float* __restrict__ W, ushort* __restrict__ Wb,
    int e, int n, int nbin, int npre) {
    mega_body(blockIdx.x, threadIdx.x, src, dst, gCursor, tmp, feat, featb,
              W, Wb, e, n, nbin, npre);
}

__global__ __launch_bounds__(TPB_F) void bucket_csr_kernel(
    const unsigned* __restrict__ tmp, const int* __restrict__ gCursor,
    int2* __restrict__ rsdeg, float* __restrict__ norm, int* __restrict__ csr,
    int n) {
    bucket_body(blockIdx.x, threadIdx.x, tmp, gCursor, rsdeg, norm, csr, n);
}

__global__ __launch_bounds__(TPB, 8) void spmm_kernel(
    const uint4* __restrict__ hin4, const int2* __restrict__ rsdeg,
    const int* __restrict__ csr, const float* __restrict__ norm,
    unsigned* __restrict__ hout, int n) {
    spmm_body(hin4, rsdeg, csr, norm, hout, n, TPB);
}

// ---------------- GEMM: out[n][128] = [featb|h1b|h2b] @ Wb^T + b -----------
// 4 waves/block; wave owns a 32-col W slice in registers (24 bf16 frags).
// A frag: row m=lane&15, k=(lane>>4)*8+j.  C/D: col=lane&15, row=(lane>>4)*4+reg.
// Round 12: nontemporal C stores (51MB streamed, never re-read).
__global__ __launch_bounds__(TPB) void gemm_mfma_kernel(
    const ushort* __restrict__ featb, const ushort* __restrict__ h1b,
    const ushort* __restrict__ h2b, const ushort* __restrict__ Wb,
    const float* __restrict__ bias, float* __restrict__ out, int n, int ntiles) {
    int lane = threadIdx.x & 63;
    int wave = threadIdx.x >> 6;
    int m = lane & 15, q = lane >> 4;

    short8 b[12][2];
#pragma unroll
    for (int ks = 0; ks < 12; ++ks)
#pragma unroll
        for (int t = 0; t < 2; ++t)
            b[ks][t] = *(const short8*)(Wb + (size_t)(wave * 32 + t * 16 + m) * 384
                                        + ks * 32 + q * 8);
    float bv0 = bias[wave * 32 + m];
    float bv1 = bias[wave * 32 + 16 + m];

    const ushort* srcs[3] = {featb, h1b, h2b};

    for (int tile = blockIdx.x; tile < ntiles; tile += gridDim.x) {
        int row = tile * 16 + m;
        bool va = row < n;
        size_t arow = (size_t)row * D;
        short8 a[12] = {};
        if (va) {
#pragma unroll
            for (int ks = 0; ks < 12; ++ks)
                a[ks] = *(const short8*)(srcs[ks >> 2] + arow + (ks & 3) * 32 + q * 8);
        }
        f32x4 acc0 = {}, acc1 = {};
#pragma unroll
        for (int ks = 0; ks < 12; ++ks) {
            acc0 = __builtin_amdgcn_mfma_f32_16x16x32_bf16(a[ks], b[ks][0], acc0, 0, 0, 0);
            acc1 = __builtin_amdgcn_mfma_f32_16x16x32_bf16(a[ks], b[ks][1], acc1, 0, 0, 0);
        }
        int r0 = tile * 16 + q * 4;
#pragma unroll
        for (int r = 0; r < 4; ++r) {
            int rw = r0 + r;
            if (rw < n) {
                size_t o = (size_t)rw * D + wave * 32 + m;
                __builtin_nontemporal_store(acc0[r] + bv0, &out[o]);
                __builtin_nontemporal_store(acc1[r] + bv1, &out[o + 16]);
            }
        }
    }
}

extern "C" void kernel_launch(void* const* d_in, const int* in_sizes, int n_in,
                              void* d_out, int out_size, void* d_ws, size_t ws_size,
                              hipStream_t stream) {
    const float* feat = (const float*)d_in[0];
    const int* src    = (const int*)d_in[1];
    const int* dst    = (const int*)d_in[2];
    const float* W    = (const float*)d_in[3];
    const float* bias = (const float*)d_in[4];
    float* out        = (float*)d_out;

    int N = in_sizes[0] / D;        // 100000
    int E = in_sizes[1];            // 1600000
    int NB = (N + BSZ - 1) >> BSH;  // 196

    char* ws = (char*)d_ws;
    size_t off = 0;
    auto bump = [&](size_t bytes) {
        char* p = ws + off;
        off += (bytes + 255) & ~(size_t)255;
        return p;
    };
    int* gCursor     = (int*)bump((size_t)NBMAX * 4);            // memset to 0
    int* bar         = (int*)bump((size_t)BAR_INTS * 4);         // memset to 0
    float* norm      = (float*)bump((size_t)N * 4);
    int2* rsdeg      = (int2*)bump((size_t)N * 8);
    unsigned* tmp    = (unsigned*)bump((size_t)NB * LCAP * 4);   // 12.85 MB
    int* csr         = (int*)bump((size_t)NB * LCAP * 4);        // 12.85 MB
    unsigned* featb  = (unsigned*)bump((size_t)N * 64 * 4);      // bf16x2 rows
    unsigned* h1b    = (unsigned*)bump((size_t)N * 64 * 4);
    unsigned* h2b    = (unsigned*)bump((size_t)N * 64 * 4);
    ushort* Wb       = (ushort*)bump((size_t)D * 384 * 2);
    (void)ws_size;

    // zero gCursor + barrier state (contiguous in ws)
    hipMemsetAsync(gCursor, 0, (size_t)NBMAX * 4 + (size_t)BAR_INTS * 4, stream);

    int nbin = (E + CH - 1) / CH;                    // 391
    int npre = (N * 64 + TPB_F - 1) / TPB_F;         // 12500
    int nwcv = (D * 384 / 4 + TPB_F - 1) / TPB_F;    // 24
    int total1 = nbin + npre + nwcv;

    // mode: 0 = untried, 1 = cooperative, 2 = fallback
    static int s_mode = 0;
    static int s_grid = 0;
    if (s_mode == 0) {
        int bpc = 0;
        if (hipOccupancyMaxActiveBlocksPerMultiprocessor(&bpc, fused_kernel,
                                                         TPB_F, 0) != hipSuccess ||
            bpc < 1)
            bpc = 1;
        long g = (long)bpc * 256;                    // 256 CUs
        if (g > 1024) g = 1024;                      // 4 blk/CU x 256
        g &= ~7L;                                    // multiple of NGRP
        if (g < 8) g = 8;
        s_grid = (int)g;
    }

    if (s_mode != 2) {
        void* args[] = {&src, &dst, &gCursor, &bar, &tmp, &feat, &featb, &W, &Wb,
                        &rsdeg, &norm, &csr, &h1b, &h2b,
                        &E, &N, &nbin, &npre, &total1, &NB, &s_grid};
        hipError_t le = hipLaunchCooperativeKernel(
            fused_kernel, dim3(s_grid), dim3(TPB_F), args, 0u, stream);
        s_mode = (le == hipSuccess) ? 1 : 2;
    }

    if (s_mode == 2) {
        // 6-dispatch fallback pipeline
        mega_kernel<<<total1, TPB_F, 0, stream>>>(
            src, dst, gCursor, tmp, feat, featb, W, Wb, E, N, nbin, npre);
        bucket_csr_kernel<<<NB, TPB_F, 0, stream>>>(tmp, gCursor, rsdeg, norm, csr, N);
        const int spmm_blocks = (N * 64 + TPB - 1) / TPB;
        spmm_kernel<<<spmm_blocks, TPB, 0, stream>>>(
            (const uint4*)featb, rsdeg, csr, norm, h1b, N);
        spmm_kernel<<<spmm_blocks, TPB, 0, stream>>>(
            (const uint4*)h1b, rsdeg, csr, norm, h2b, N);
    }

    const int ntiles = (N + 15) / 16;                // 6250
    gemm_mfma_kernel<<<GEMM_GRID, TPB, 0, stream>>>(
        (const ushort*)featb, (const ushort*)h1b, (const ushort*)h2b,
        Wb, bias, out, N, ntiles);
}

// Round 6
// 393.364 us; speedup vs baseline: 1.7667x; 1.7667x over previous
//
#include <hip/hip_runtime.h>
#include <hip/hip_bf16.h>

// TAGConv K=2, D=128. Round 13: fusion attempt #3.
// r1 (cg::grid.sync) and r5 (hand barrier, ACQ_REL/ACQUIRE + per-block
// threadfence) both ~950us with VALU 7%, BW 0.54TB/s, fetch NOT inflated:
// everyone parked, caches intact -> the cost is the per-block cache
// maintenance (agent acquire poll => buffer_inv; threadfence => wbl2+inv;
// ~6K L2 tag-walks per launch serialized per XCD). Fix: barrier state only
// ever touched by atomics (memory-side LLC; relaxed polls never hit L2),
// and exactly ONE CAS-winner per XCD (s_getreg XCC_ID) runs __threadfence()
// per barrier: 8 wb/inv walks instead of 2048. Phase bodies identical to
// r5 (passed). gemm separate (VGPR isolation) + nontemporal C stores.
// Pipeline: memset(2.8KB) -> fused(coop, 3 xbar) -> gemm.

#define D 128
#define TPB 256              // fallback spmm / gemm block
#define TPB_F 512            // fused kernel block (8 waves)
#define GEMM_GRID 768

#define BSH 9
#define BSZ 512              // nodes per bucket
#define NBMAX 256            // max buckets
#define EPT 8                // edges per thread in binscatter
#define CH (TPB_F * EPT)     // 4096 edges per chunk
#define LCAP 16384           // fixed per-bucket region (avg fill ~8.2K)

// barrier state layout (ints; one 128B line per counter)
#define XB_ACNT 0            // 8 group arrival lines: [g*32]
#define XB_ROOT (8 * 32)
#define XB_REL1 (9 * 32)
#define XB_CLAIM (10 * 32)   // 8 per-XCD claim lines: [10*32 + xcd*32]
#define XB_WDONE (18 * 32)
#define XB_REL2 (19 * 32)
#define BAR_INTS (20 * 32)

typedef __attribute__((ext_vector_type(8))) short short8;
typedef __attribute__((ext_vector_type(4))) float f32x4;

__device__ __forceinline__ ushort f2bf(float f) {
    unsigned u = __float_as_uint(f);
    u += 0x7fff + ((u >> 16) & 1);      // round-to-nearest-even
    return (ushort)(u >> 16);
}
__device__ __forceinline__ unsigned pack2bf(float x, float y) {
    return (unsigned)f2bf(x) | ((unsigned)f2bf(y) << 16);
}
__device__ __forceinline__ float bf_lo(unsigned v) { return __uint_as_float(v << 16); }
__device__ __forceinline__ float bf_hi(unsigned v) { return __uint_as_float(v & 0xffff0000u); }

// ---------------- grid barrier, XCD-level fencing ----------------
// All counters monotonic (zeroed once per launch by host memset; barrier k
// uses threshold (k+1)*count). bar lines are ONLY ever accessed by atomics
// -> never resident in any L2 -> relaxed polls read LLC fresh, no cache-op
// per poll. Data visibility: after global arrival (all waves' writes are in
// their L2 - compiler drains vmcnt before s_barrier), one CAS-winner per
// XCD runs __threadfence() (wbl2+inv, cache-wide for its XCD), then counts
// into WDONE; REL2 releases everyone only after all 8 XCDs are flushed and
// invalidated. Consumers poll LLC until then, so no stale refill possible.
__device__ __forceinline__ void xbar(int* bar, int k, int nbg) {
    __syncthreads();
    if (threadIdx.x == 0) {
        int grp = (int)(blockIdx.x & 7);
        int a = atomicAdd(&bar[XB_ACNT + grp * 32], 1);
        if (a == nbg * (k + 1) - 1) {                 // last of my group
            int r = atomicAdd(&bar[XB_ROOT], 1);
            if (r == 8 * (k + 1) - 1)                 // last group overall
                atomicExch(&bar[XB_REL1], k + 1);
        }
        while (__hip_atomic_load(&bar[XB_REL1], __ATOMIC_RELAXED,
                                 __HIP_MEMORY_SCOPE_AGENT) < k + 1)
            __builtin_amdgcn_s_sleep(8);
        int xcd;
        asm volatile("s_getreg_b32 %0, hwreg(HW_REG_XCC_ID)" : "=s"(xcd));
        xcd &= 7;
        if (atomicCAS(&bar[XB_CLAIM + xcd * 32], k, k + 1) == k) {
            __threadfence();                          // ONE wbl2+inv per XCD
            int d = atomicAdd(&bar[XB_WDONE], 1);
            if (d == 8 * (k + 1) - 1)
                atomicExch(&bar[XB_REL2], k + 1);
        }
        while (__hip_atomic_load(&bar[XB_REL2], __ATOMIC_RELAXED,
                                 __HIP_MEMORY_SCOPE_AGENT) < k + 1)
            __builtin_amdgcn_s_sleep(8);
    }
    __syncthreads();
}

// ---------------- phase bodies (512-thread versions, r5-proven) ----------

__device__ __forceinline__ void mega_body(
    int bid, int t,
    const int* __restrict__ src, const int* __restrict__ dst,
    int* __restrict__ gCursor, unsigned* __restrict__ tmp,
    const float* __restrict__ feat, unsigned* __restrict__ featb,
    const float* __restrict__ W, ushort* __restrict__ Wb,
    int e, int n, int nbin, int npre) {
    __shared__ int hist[NBMAX];
    __shared__ int cellBase[NBMAX];
    if (bid < nbin) {
        if (t < NBMAX) hist[t] = 0;
        __syncthreads();
        int base = bid * CH;
        int b[EPT]; unsigned pk[EPT]; int r[EPT];
#pragma unroll
        for (int k = 0; k < EPT; ++k) {
            int i = base + k * TPB_F + t;
            b[k] = -1;
            if (i < e) {
                int d = dst[i];
                b[k] = d >> BSH;
                pk[k] = ((unsigned)src[i] << BSH) | (unsigned)(d & (BSZ - 1));
                r[k] = atomicAdd(&hist[b[k]], 1);
            }
        }
        __syncthreads();
        if (t < NBMAX) {
            int h = hist[t];
            cellBase[t] = h ? t * LCAP + atomicAdd(&gCursor[t], h) : 0;
        }
        __syncthreads();
#pragma unroll
        for (int k = 0; k < EPT; ++k)
            if (b[k] >= 0) tmp[cellBase[b[k]] + r[k]] = pk[k];
        __syncthreads();            // LDS reuse guard (grid-stride loop)
    } else if (bid < nbin + npre) {
        int gid = (bid - nbin) * TPB_F + t;
        int node = gid >> 6, c = gid & 63;
        if (node < n) {
            float2 f = ((const float2*)(feat + (size_t)node * D))[c];
            featb[(size_t)node * 64 + c] = pack2bf(f.x, f.y);
        }
    } else {
        int i = ((bid - nbin - npre) * TPB_F + t) * 4;   // D*384 = 49152 elems
        float4 w = *(const float4*)(W + i);
        ushort4 o;
        o.x = f2bf(w.x); o.y = f2bf(w.y); o.z = f2bf(w.z); o.w = f2bf(w.w);
        *(ushort4*)(Wb + i) = o;
    }
}

__device__ __forceinline__ void bucket_body(
    int bkt, int t,
    const unsigned* __restrict__ tmp, const int* __restrict__ gCursor,
    int2* __restrict__ rsdeg, float* __restrict__ norm, int* __restrict__ csr,
    int n) {
    __shared__ int cnt[BSZ];
    __shared__ int off[BSZ];
    __shared__ int pr[BSZ];
    int beg = bkt * LCAP;
    int m = gCursor[bkt];
    int end = beg + m;
    cnt[t] = 0;
    __syncthreads();
    for (int i = beg + t; i < end; i += TPB_F)
        atomicAdd(&cnt[tmp[i] & (BSZ - 1)], 1);
    __syncthreads();
    int own = cnt[t];
    pr[t] = own;
    __syncthreads();
    for (int o = 1; o < BSZ; o <<= 1) {
        int x = (t >= o) ? pr[t - o] : 0;
        __syncthreads();
        pr[t] += x;
        __syncthreads();
    }
    off[t] = pr[t] - own;
    __syncthreads();
    cnt[t] = 0;                            // reuse as rank counters
    __syncthreads();
    for (int i = beg + t; i < end; i += TPB_F) {
        unsigned v = tmp[i];
        int l = v & (BSZ - 1);
        int r = atomicAdd(&cnt[l], 1);
        int idx = off[l] + r;
        if (idx < LCAP) csr[beg + idx] = (int)(v >> BSH);
    }
    __syncthreads();
    int node0 = bkt << BSH;
    {
        int node = node0 + t;
        if (node < n) {
            rsdeg[node] = make_int2(beg + off[t], cnt[t]);
            norm[node] = rsqrtf((float)cnt[t]);
        }
    }
    __syncthreads();                       // LDS reuse guard
}

__device__ __forceinline__ void spmm_body(
    const uint4* __restrict__ hin4, const int2* __restrict__ rsdeg,
    const int* __restrict__ csr, const float* __restrict__ norm,
    unsigned* __restrict__ hout, int n, int tpb) {
    int gw = (int)((blockIdx.x * tpb + threadIdx.x) >> 6);
    int nw = (int)((gridDim.x * tpb) >> 6);
    int lane = threadIdx.x & 63;
    int q = lane >> 4;
    int c = lane & 15;
    for (int w = gw; w < n; w += nw) {
        int2 rd = rsdeg[w];
        int beg = rd.x, end = rd.x + rd.y;
        float acc[8] = {};
#pragma unroll 4
        for (int j = beg + q; j < end; j += 4) {
            int u = csr[j];
            float s = norm[u];
            uint4 v = hin4[(u << 4) + c];
            acc[0] = fmaf(s, bf_lo(v.x), acc[0]);
            acc[1] = fmaf(s, bf_hi(v.x), acc[1]);
            acc[2] = fmaf(s, bf_lo(v.y), acc[2]);
            acc[3] = fmaf(s, bf_hi(v.y), acc[3]);
            acc[4] = fmaf(s, bf_lo(v.z), acc[4]);
            acc[5] = fmaf(s, bf_hi(v.z), acc[5]);
            acc[6] = fmaf(s, bf_lo(v.w), acc[6]);
            acc[7] = fmaf(s, bf_hi(v.w), acc[7]);
        }
#pragma unroll
        for (int k = 0; k < 8; ++k) {
            acc[k] += __shfl_xor(acc[k], 16, 64);
            acc[k] += __shfl_xor(acc[k], 32, 64);
        }
        if (q == 0) {
            float nv = norm[w];
            uint4 r;
            r.x = pack2bf(acc[0] * nv, acc[1] * nv);
            r.y = pack2bf(acc[2] * nv, acc[3] * nv);
            r.z = pack2bf(acc[4] * nv, acc[5] * nv);
            r.w = pack2bf(acc[6] * nv, acc[7] * nv);
            *(uint4*)(hout + (size_t)w * 64 + c * 4) = r;
        }
    }
}

// ---------------- fused cooperative kernel ----------------
__global__ __launch_bounds__(TPB_F, 8) void fused_kernel(
    const int* __restrict__ src, const int* __restrict__ dst,
    int* __restrict__ gCursor, int* __restrict__ bar, unsigned* __restrict__ tmp,
    const float* __restrict__ feat, unsigned* __restrict__ featb,
    const float* __restrict__ W, ushort* __restrict__ Wb,
    int2* __restrict__ rsdeg, float* __restrict__ norm, int* __restrict__ csr,
    unsigned* __restrict__ h1b, unsigned* __restrict__ h2b,
    int e, int n, int nbin, int npre, int total1, int nb, int nbg) {
    int t = threadIdx.x;

    // phase 1: binscatter || prescale || wconv (gCursor pre-zeroed by memset)
    for (int bid = blockIdx.x; bid < total1; bid += gridDim.x)
        mega_body(bid, t, src, dst, gCursor, tmp, feat, featb, W, Wb,
                  e, n, nbin, npre);
    xbar(bar, 0, nbg);

    // phase 2: per-bucket CSR
    for (int bkt = blockIdx.x; bkt < nb; bkt += gridDim.x)
        bucket_body(bkt, t, tmp, gCursor, rsdeg, norm, csr, n);
    xbar(bar, 1, nbg);

    // phase 3: hop 1
    spmm_body((const uint4*)featb, rsdeg, csr, norm, h1b, n, TPB_F);
    xbar(bar, 2, nbg);

    // phase 4: hop 2
    spmm_body((const uint4*)h1b, rsdeg, csr, norm, h2b, n, TPB_F);
}

// ---------------- fallback wrappers (non-cooperative path) ----------------
__global__ __launch_bounds__(TPB_F) void mega_kernel(
    const int* __restrict__ src, const int* __restrict__ dst,
    int* __restrict__ gCursor, unsigned* __restrict__ tmp,
    const float* __restrict__ feat, unsigned* __restrict__ featb,
    const float* __restrict__ W, ushort* __restrict__ Wb,
    int e, int n, int nbin, int npre) {
    mega_body(blockIdx.x, threadIdx.x, src, dst, gCursor, tmp, feat, featb,
              W, Wb, e, n, nbin, npre);
}

__global__ __launch_bounds__(TPB_F) void bucket_csr_kernel(
    const unsigned* __restrict__ tmp, const int* __restrict__ gCursor,
    int2* __restrict__ rsdeg, float* __restrict__ norm, int* __restrict__ csr,
    int n) {
    bucket_body(blockIdx.x, threadIdx.x, tmp, gCursor, rsdeg, norm, csr, n);
}

__global__ __launch_bounds__(TPB, 8) void spmm_kernel(
    const uint4* __restrict__ hin4, const int2* __restrict__ rsdeg,
    const int* __restrict__ csr, const float* __restrict__ norm,
    unsigned* __restrict__ hout, int n) {
    spmm_body(hin4, rsdeg, csr, norm, hout, n, TPB);
}

// ---------------- GEMM: out[n][128] = [featb|h1b|h2b] @ Wb^T + b -----------
// 4 waves/block; wave owns a 32-col W slice in registers (24 bf16 frags).
// A frag: row m=lane&15, k=(lane>>4)*8+j.  C/D: col=lane&15, row=(lane>>4)*4+reg.
// Nontemporal C stores (51MB streamed, never re-read).
__global__ __launch_bounds__(TPB) void gemm_mfma_kernel(
    const ushort* __restrict__ featb, const ushort* __restrict__ h1b,
    const ushort* __restrict__ h2b, const ushort* __restrict__ Wb,
    const float* __restrict__ bias, float* __restrict__ out, int n, int ntiles) {
    int lane = threadIdx.x & 63;
    int wave = threadIdx.x >> 6;
    int m = lane & 15, q = lane >> 4;

    short8 b[12][2];
#pragma unroll
    for (int ks = 0; ks < 12; ++ks)
#pragma unroll
        for (int t = 0; t < 2; ++t)
            b[ks][t] = *(const short8*)(Wb + (size_t)(wave * 32 + t * 16 + m) * 384
                                        + ks * 32 + q * 8);
    float bv0 = bias[wave * 32 + m];
    float bv1 = bias[wave * 32 + 16 + m];

    const ushort* srcs[3] = {featb, h1b, h2b};

    for (int tile = blockIdx.x; tile < ntiles; tile += gridDim.x) {
        int row = tile * 16 + m;
        bool va = row < n;
        size_t arow = (size_t)row * D;
        short8 a[12] = {};
        if (va) {
#pragma unroll
            for (int ks = 0; ks < 12; ++ks)
                a[ks] = *(const short8*)(srcs[ks >> 2] + arow + (ks & 3) * 32 + q * 8);
        }
        f32x4 acc0 = {}, acc1 = {};
#pragma unroll
        for (int ks = 0; ks < 12; ++ks) {
            acc0 = __builtin_amdgcn_mfma_f32_16x16x32_bf16(a[ks], b[ks][0], acc0, 0, 0, 0);
            acc1 = __builtin_amdgcn_mfma_f32_16x16x32_bf16(a[ks], b[ks][1], acc1, 0, 0, 0);
        }
        int r0 = tile * 16 + q * 4;
#pragma unroll
        for (int r = 0; r < 4; ++r) {
            int rw = r0 + r;
            if (rw < n) {
                size_t o = (size_t)rw * D + wave * 32 + m;
                __builtin_nontemporal_store(acc0[r] + bv0, &out[o]);
                __builtin_nontemporal_store(acc1[r] + bv1, &out[o + 16]);
            }
        }
    }
}

extern "C" void kernel_launch(void* const* d_in, const int* in_sizes, int n_in,
                              void* d_out, int out_size, void* d_ws, size_t ws_size,
                              hipStream_t stream) {
    const float* feat = (const float*)d_in[0];
    const int* src    = (const int*)d_in[1];
    const int* dst    = (const int*)d_in[2];
    const float* W    = (const float*)d_in[3];
    const float* bias = (const float*)d_in[4];
    float* out        = (float*)d_out;

    int N = in_sizes[0] / D;        // 100000
    int E = in_sizes[1];            // 1600000
    int NB = (N + BSZ - 1) >> BSH;  // 196

    char* ws = (char*)d_ws;
    size_t off = 0;
    auto bump = [&](size_t bytes) {
        char* p = ws + off;
        off += (bytes + 255) & ~(size_t)255;
        return p;
    };
    int* gCursor     = (int*)bump((size_t)NBMAX * 4);            // memset to 0
    int* bar         = (int*)bump((size_t)BAR_INTS * 4);         // memset to 0
    float* norm      = (float*)bump((size_t)N * 4);
    int2* rsdeg      = (int2*)bump((size_t)N * 8);
    unsigned* tmp    = (unsigned*)bump((size_t)NB * LCAP * 4);   // 12.85 MB
    int* csr         = (int*)bump((size_t)NB * LCAP * 4);        // 12.85 MB
    unsigned* featb  = (unsigned*)bump((size_t)N * 64 * 4);      // bf16x2 rows
    unsigned* h1b    = (unsigned*)bump((size_t)N * 64 * 4);
    unsigned* h2b    = (unsigned*)bump((size_t)N * 64 * 4);
    ushort* Wb       = (ushort*)bump((size_t)D * 384 * 2);
    (void)ws_size;

    // zero gCursor + barrier state (contiguous in ws); the dispatch boundary
    // after the memset flushes any blit-dirtied L2 lines before fused runs.
    hipMemsetAsync(gCursor, 0, (size_t)NBMAX * 4 + 256 + (size_t)BAR_INTS * 4,
                   stream);

    int nbin = (E + CH - 1) / CH;                    // 391
    int npre = (N * 64 + TPB_F - 1) / TPB_F;         // 12500
    int nwcv = (D * 384 / 4 + TPB_F - 1) / TPB_F;    // 24
    int total1 = nbin + npre + nwcv;

    // mode: 0 = untried, 1 = cooperative, 2 = fallback
    static int s_mode = 0;
    static int s_grid = 0;
    if (s_mode == 0) {
        int bpc = 0;
        if (hipOccupancyMaxActiveBlocksPerMultiprocessor(&bpc, fused_kernel,
                                                         TPB_F, 0) != hipSuccess ||
            bpc < 1) {
            s_mode = 2;
        } else {
            long g = (long)bpc * 256;                // 256 CUs
            if (g > 1024) g = 1024;                  // 4 blk/CU x 256
            g &= ~7L;                                // multiple of 8 groups
            if (g < 8) { s_mode = 2; } else { s_grid = (int)g; }
        }
    }

    if (s_mode != 2) {
        int nbg = s_grid >> 3;                       // blocks per arrival group
        void* args[] = {&src, &dst, &gCursor, &bar, &tmp, &feat, &featb, &W, &Wb,
                        &rsdeg, &norm, &csr, &h1b, &h2b,
                        &E, &N, &nbin, &npre, &total1, &NB, &nbg};
        hipError_t le = hipLaunchCooperativeKernel(
            fused_kernel, dim3(s_grid), dim3(TPB_F), args, 0u, stream);
        s_mode = (le == hipSuccess) ? 1 : 2;
    }

    if (s_mode == 2) {
        // 5-dispatch fallback pipeline
        mega_kernel<<<total1, TPB_F, 0, stream>>>(
            src, dst, gCursor, tmp, feat, featb, W, Wb, E, N, nbin, npre);
        bucket_csr_kernel<<<NB, TPB_F, 0, stream>>>(tmp, gCursor, rsdeg, norm, csr, N);
        const int spmm_blocks = (N * 64 + TPB - 1) / TPB;
        spmm_kernel<<<spmm_blocks, TPB, 0, stream>>>(
            (const uint4*)featb, rsdeg, csr, norm, h1b, N);
        spmm_kernel<<<spmm_blocks, TPB, 0, stream>>>(
            (const uint4*)h1b, rsdeg, csr, norm, h2b, N);
    }

    const int ntiles = (N + 15) / 16;                // 6250
    gemm_mfma_kernel<<<GEMM_GRID, TPB, 0, stream>>>(
        (const ushort*)featb, (const ushort*)h1b, (const ushort*)h2b,
        Wb, bias, out, N, ntiles);
}

// Round 7
// 365.600 us; speedup vs baseline: 1.9009x; 1.0759x over previous
//
#include <hip/hip_runtime.h>
#include <hip/hip_bf16.h>

// TAGConv K=2, D=128. Round 14.
// r6 result: fused kernel body = 194us (barrier theory VALIDATED: 3 xbar
// barriers ~25us total vs ~750us for cg/per-block-fence versions). But
// total 393us: ~170us of serialization AROUND the cooperative launch
// (ROCm coop-launch drains the device to guarantee co-residency).
// Fix: launch the SAME fused kernel as a plain kernel. Co-residency is
// guaranteed arithmetically: grid = bpc*256 (occupancy API; bpc=4 at
// VGPR32/LDS8KB/__launch_bounds__(512,8)) <= device capacity, all slots
// free at dispatch -> all blocks resident immediately. xbar already
// handles cross-XCD visibility itself. Spin loops get a bailout so any
// co-residency surprise fails the numeric check instead of hanging.
// Pipeline: memset(2.8KB) -> fused(plain, 3 xbar) -> gemm.

#define D 128
#define TPB 256              // fallback spmm / gemm block
#define TPB_F 512            // fused kernel block (8 waves)
#define GEMM_GRID 768

#define BSH 9
#define BSZ 512              // nodes per bucket
#define NBMAX 256            // max buckets
#define EPT 8                // edges per thread in binscatter
#define CH (TPB_F * EPT)     // 4096 edges per chunk
#define LCAP 16384           // fixed per-bucket region (avg fill ~8.2K)

// barrier state layout (ints; one 128B line per counter)
#define XB_ACNT 0            // 8 group arrival lines: [g*32]
#define XB_ROOT (8 * 32)
#define XB_REL1 (9 * 32)
#define XB_CLAIM (10 * 32)   // 8 per-XCD claim lines: [10*32 + xcd*32]
#define XB_WDONE (18 * 32)
#define XB_REL2 (19 * 32)
#define BAR_INTS (20 * 32)

typedef __attribute__((ext_vector_type(8))) short short8;
typedef __attribute__((ext_vector_type(4))) float f32x4;

__device__ __forceinline__ ushort f2bf(float f) {
    unsigned u = __float_as_uint(f);
    u += 0x7fff + ((u >> 16) & 1);      // round-to-nearest-even
    return (ushort)(u >> 16);
}
__device__ __forceinline__ unsigned pack2bf(float x, float y) {
    return (unsigned)f2bf(x) | ((unsigned)f2bf(y) << 16);
}
__device__ __forceinline__ float bf_lo(unsigned v) { return __uint_as_float(v << 16); }
__device__ __forceinline__ float bf_hi(unsigned v) { return __uint_as_float(v & 0xffff0000u); }

// ---------------- grid barrier, XCD-level fencing (r6-proven) -------------
// All counters monotonic (zeroed once per launch by host memset; barrier k
// uses threshold (k+1)*count). bar lines are ONLY ever accessed by atomics
// -> never L2-resident -> relaxed polls read LLC fresh, no cache-op per
// poll. After global arrival, ONE CAS-winner per XCD runs __threadfence()
// (wbl2+inv for its XCD: 8 walks/barrier instead of 2048); REL2 releases
// everyone only after all 8 XCDs flushed+invalidated. Spin caps: a missing
// release degrades to wrong results (visible) instead of a hang.
__device__ __forceinline__ void xbar(int* bar, int k, int nbg) {
    __syncthreads();
    if (threadIdx.x == 0) {
        int grp = (int)(blockIdx.x & 7);
        int a = atomicAdd(&bar[XB_ACNT + grp * 32], 1);
        if (a == nbg * (k + 1) - 1) {                 // last of my group
            int r = atomicAdd(&bar[XB_ROOT], 1);
            if (r == 8 * (k + 1) - 1)                 // last group overall
                atomicExch(&bar[XB_REL1], k + 1);
        }
        for (long it = 0;
             __hip_atomic_load(&bar[XB_REL1], __ATOMIC_RELAXED,
                               __HIP_MEMORY_SCOPE_AGENT) < k + 1; ++it) {
            __builtin_amdgcn_s_sleep(8);
            if (it > (1L << 22)) break;               // ~>100ms safety valve
        }
        int xcd;
        asm volatile("s_getreg_b32 %0, hwreg(HW_REG_XCC_ID)" : "=s"(xcd));
        xcd &= 7;
        if (atomicCAS(&bar[XB_CLAIM + xcd * 32], k, k + 1) == k) {
            __threadfence();                          // ONE wbl2+inv per XCD
            int d = atomicAdd(&bar[XB_WDONE], 1);
            if (d == 8 * (k + 1) - 1)
                atomicExch(&bar[XB_REL2], k + 1);
        }
        for (long it = 0;
             __hip_atomic_load(&bar[XB_REL2], __ATOMIC_RELAXED,
                               __HIP_MEMORY_SCOPE_AGENT) < k + 1; ++it) {
            __builtin_amdgcn_s_sleep(8);
            if (it > (1L << 22)) break;               // safety valve
        }
    }
    __syncthreads();
}

// ---------------- phase bodies (512-thread versions, r5/r6-proven) --------

__device__ __forceinline__ void mega_body(
    int bid, int t,
    const int* __restrict__ src, const int* __restrict__ dst,
    int* __restrict__ gCursor, unsigned* __restrict__ tmp,
    const float* __restrict__ feat, unsigned* __restrict__ featb,
    const float* __restrict__ W, ushort* __restrict__ Wb,
    int e, int n, int nbin, int npre) {
    __shared__ int hist[NBMAX];
    __shared__ int cellBase[NBMAX];
    if (bid < nbin) {
        if (t < NBMAX) hist[t] = 0;
        __syncthreads();
        int base = bid * CH;
        int b[EPT]; unsigned pk[EPT]; int r[EPT];
#pragma unroll
        for (int k = 0; k < EPT; ++k) {
            int i = base + k * TPB_F + t;
            b[k] = -1;
            if (i < e) {
                int d = dst[i];
                b[k] = d >> BSH;
                pk[k] = ((unsigned)src[i] << BSH) | (unsigned)(d & (BSZ - 1));
                r[k] = atomicAdd(&hist[b[k]], 1);
            }
        }
        __syncthreads();
        if (t < NBMAX) {
            int h = hist[t];
            cellBase[t] = h ? t * LCAP + atomicAdd(&gCursor[t], h) : 0;
        }
        __syncthreads();
#pragma unroll
        for (int k = 0; k < EPT; ++k)
            if (b[k] >= 0) tmp[cellBase[b[k]] + r[k]] = pk[k];
        __syncthreads();            // LDS reuse guard (grid-stride loop)
    } else if (bid < nbin + npre) {
        int gid = (bid - nbin) * TPB_F + t;
        int node = gid >> 6, c = gid & 63;
        if (node < n) {
            float2 f = ((const float2*)(feat + (size_t)node * D))[c];
            featb[(size_t)node * 64 + c] = pack2bf(f.x, f.y);
        }
    } else {
        int i = ((bid - nbin - npre) * TPB_F + t) * 4;   // D*384 = 49152 elems
        float4 w = *(const float4*)(W + i);
        ushort4 o;
        o.x = f2bf(w.x); o.y = f2bf(w.y); o.z = f2bf(w.z); o.w = f2bf(w.w);
        *(ushort4*)(Wb + i) = o;
    }
}

__device__ __forceinline__ void bucket_body(
    int bkt, int t,
    const unsigned* __restrict__ tmp, const int* __restrict__ gCursor,
    int2* __restrict__ rsdeg, float* __restrict__ norm, int* __restrict__ csr,
    int n) {
    __shared__ int cnt[BSZ];
    __shared__ int off[BSZ];
    __shared__ int pr[BSZ];
    int beg = bkt * LCAP;
    int m = gCursor[bkt];
    int end = beg + m;
    cnt[t] = 0;
    __syncthreads();
    for (int i = beg + t; i < end; i += TPB_F)
        atomicAdd(&cnt[tmp[i] & (BSZ - 1)], 1);
    __syncthreads();
    int own = cnt[t];
    pr[t] = own;
    __syncthreads();
    for (int o = 1; o < BSZ; o <<= 1) {
        int x = (t >= o) ? pr[t - o] : 0;
        __syncthreads();
        pr[t] += x;
        __syncthreads();
    }
    off[t] = pr[t] - own;
    __syncthreads();
    cnt[t] = 0;                            // reuse as rank counters
    __syncthreads();
    for (int i = beg + t; i < end; i += TPB_F) {
        unsigned v = tmp[i];
        int l = v & (BSZ - 1);
        int r = atomicAdd(&cnt[l], 1);
        int idx = off[l] + r;
        if (idx < LCAP) csr[beg + idx] = (int)(v >> BSH);
    }
    __syncthreads();
    int node0 = bkt << BSH;
    {
        int node = node0 + t;
        if (node < n) {
            rsdeg[node] = make_int2(beg + off[t], cnt[t]);
            norm[node] = rsqrtf((float)cnt[t]);
        }
    }
    __syncthreads();                       // LDS reuse guard
}

__device__ __forceinline__ void spmm_body(
    const uint4* __restrict__ hin4, const int2* __restrict__ rsdeg,
    const int* __restrict__ csr, const float* __restrict__ norm,
    unsigned* __restrict__ hout, int n, int tpb) {
    int gw = (int)((blockIdx.x * tpb + threadIdx.x) >> 6);
    int nw = (int)((gridDim.x * tpb) >> 6);
    int lane = threadIdx.x & 63;
    int q = lane >> 4;
    int c = lane & 15;
    for (int w = gw; w < n; w += nw) {
        int2 rd = rsdeg[w];
        int beg = rd.x, end = rd.x + rd.y;
        float acc[8] = {};
#pragma unroll 4
        for (int j = beg + q; j < end; j += 4) {
            int u = csr[j];
            float s = norm[u];
            uint4 v = hin4[(u << 4) + c];
            acc[0] = fmaf(s, bf_lo(v.x), acc[0]);
            acc[1] = fmaf(s, bf_hi(v.x), acc[1]);
            acc[2] = fmaf(s, bf_lo(v.y), acc[2]);
            acc[3] = fmaf(s, bf_hi(v.y), acc[3]);
            acc[4] = fmaf(s, bf_lo(v.z), acc[4]);
            acc[5] = fmaf(s, bf_hi(v.z), acc[5]);
            acc[6] = fmaf(s, bf_lo(v.w), acc[6]);
            acc[7] = fmaf(s, bf_hi(v.w), acc[7]);
        }
#pragma unroll
        for (int k = 0; k < 8; ++k) {
            acc[k] += __shfl_xor(acc[k], 16, 64);
            acc[k] += __shfl_xor(acc[k], 32, 64);
        }
        if (q == 0) {
            float nv = norm[w];
            uint4 r;
            r.x = pack2bf(acc[0] * nv, acc[1] * nv);
            r.y = pack2bf(acc[2] * nv, acc[3] * nv);
            r.z = pack2bf(acc[4] * nv, acc[5] * nv);
            r.w = pack2bf(acc[6] * nv, acc[7] * nv);
            *(uint4*)(hout + (size_t)w * 64 + c * 4) = r;
        }
    }
}

// ---------------- fused kernel (plain launch, grid <= capacity) -----------
__global__ __launch_bounds__(TPB_F, 8) void fused_kernel(
    const int* __restrict__ src, const int* __restrict__ dst,
    int* __restrict__ gCursor, int* __restrict__ bar, unsigned* __restrict__ tmp,
    const float* __restrict__ feat, unsigned* __restrict__ featb,
    const float* __restrict__ W, ushort* __restrict__ Wb,
    int2* __restrict__ rsdeg, float* __restrict__ norm, int* __restrict__ csr,
    unsigned* __restrict__ h1b, unsigned* __restrict__ h2b,
    int e, int n, int nbin, int npre, int total1, int nb, int nbg) {
    int t = threadIdx.x;

    // phase 1: binscatter || prescale || wconv (gCursor pre-zeroed by memset)
    for (int bid = blockIdx.x; bid < total1; bid += gridDim.x)
        mega_body(bid, t, src, dst, gCursor, tmp, feat, featb, W, Wb,
                  e, n, nbin, npre);
    xbar(bar, 0, nbg);

    // phase 2: per-bucket CSR
    for (int bkt = blockIdx.x; bkt < nb; bkt += gridDim.x)
        bucket_body(bkt, t, tmp, gCursor, rsdeg, norm, csr, n);
    xbar(bar, 1, nbg);

    // phase 3: hop 1
    spmm_body((const uint4*)featb, rsdeg, csr, norm, h1b, n, TPB_F);
    xbar(bar, 2, nbg);

    // phase 4: hop 2
    spmm_body((const uint4*)h1b, rsdeg, csr, norm, h2b, n, TPB_F);
}

// ---------------- fallback wrappers (non-fused path) ----------------
__global__ __launch_bounds__(TPB_F) void mega_kernel(
    const int* __restrict__ src, const int* __restrict__ dst,
    int* __restrict__ gCursor, unsigned* __restrict__ tmp,
    const float* __restrict__ feat, unsigned* __restrict__ featb,
    const float* __restrict__ W, ushort* __restrict__ Wb,
    int e, int n, int nbin, int npre) {
    mega_body(blockIdx.x, threadIdx.x, src, dst, gCursor, tmp, feat, featb,
              W, Wb, e, n, nbin, npre);
}

__global__ __launch_bounds__(TPB_F) void bucket_csr_kernel(
    const unsigned* __restrict__ tmp, const int* __restrict__ gCursor,
    int2* __restrict__ rsdeg, float* __restrict__ norm, int* __restrict__ csr,
    int n) {
    bucket_body(blockIdx.x, threadIdx.x, tmp, gCursor, rsdeg, norm, csr, n);
}

__global__ __launch_bounds__(TPB, 8) void spmm_kernel(
    const uint4* __restrict__ hin4, const int2* __restrict__ rsdeg,
    const int* __restrict__ csr, const float* __restrict__ norm,
    unsigned* __restrict__ hout, int n) {
    spmm_body(hin4, rsdeg, csr, norm, hout, n, TPB);
}

// ---------------- GEMM: out[n][128] = [featb|h1b|h2b] @ Wb^T + b -----------
// 4 waves/block; wave owns a 32-col W slice in registers (24 bf16 frags).
// A frag: row m=lane&15, k=(lane>>4)*8+j.  C/D: col=lane&15, row=(lane>>4)*4+reg.
// Nontemporal C stores (51MB streamed, never re-read).
__global__ __launch_bounds__(TPB) void gemm_mfma_kernel(
    const ushort* __restrict__ featb, const ushort* __restrict__ h1b,
    const ushort* __restrict__ h2b, const ushort* __restrict__ Wb,
    const float* __restrict__ bias, float* __restrict__ out, int n, int ntiles) {
    int lane = threadIdx.x & 63;
    int wave = threadIdx.x >> 6;
    int m = lane & 15, q = lane >> 4;

    short8 b[12][2];
#pragma unroll
    for (int ks = 0; ks < 12; ++ks)
#pragma unroll
        for (int t = 0; t < 2; ++t)
            b[ks][t] = *(const short8*)(Wb + (size_t)(wave * 32 + t * 16 + m) * 384
                                        + ks * 32 + q * 8);
    float bv0 = bias[wave * 32 + m];
    float bv1 = bias[wave * 32 + 16 + m];

    const ushort* srcs[3] = {featb, h1b, h2b};

    for (int tile = blockIdx.x; tile < ntiles; tile += gridDim.x) {
        int row = tile * 16 + m;
        bool va = row < n;
        size_t arow = (size_t)row * D;
        short8 a[12] = {};
        if (va) {
#pragma unroll
            for (int ks = 0; ks < 12; ++ks)
                a[ks] = *(const short8*)(srcs[ks >> 2] + arow + (ks & 3) * 32 + q * 8);
        }
        f32x4 acc0 = {}, acc1 = {};
#pragma unroll
        for (int ks = 0; ks < 12; ++ks) {
            acc0 = __builtin_amdgcn_mfma_f32_16x16x32_bf16(a[ks], b[ks][0], acc0, 0, 0, 0);
            acc1 = __builtin_amdgcn_mfma_f32_16x16x32_bf16(a[ks], b[ks][1], acc1, 0, 0, 0);
        }
        int r0 = tile * 16 + q * 4;
#pragma unroll
        for (int r = 0; r < 4; ++r) {
            int rw = r0 + r;
            if (rw < n) {
                size_t o = (size_t)rw * D + wave * 32 + m;
                __builtin_nontemporal_store(acc0[r] + bv0, &out[o]);
                __builtin_nontemporal_store(acc1[r] + bv1, &out[o + 16]);
            }
        }
    }
}

extern "C" void kernel_launch(void* const* d_in, const int* in_sizes, int n_in,
                              void* d_out, int out_size, void* d_ws, size_t ws_size,
                              hipStream_t stream) {
    const float* feat = (const float*)d_in[0];
    const int* src    = (const int*)d_in[1];
    const int* dst    = (const int*)d_in[2];
    const float* W    = (const float*)d_in[3];
    const float* bias = (const float*)d_in[4];
    float* out        = (float*)d_out;

    int N = in_sizes[0] / D;        // 100000
    int E = in_sizes[1];            // 1600000
    int NB = (N + BSZ - 1) >> BSH;  // 196

    char* ws = (char*)d_ws;
    size_t off = 0;
    auto bump = [&](size_t bytes) {
        char* p = ws + off;
        off += (bytes + 255) & ~(size_t)255;
        return p;
    };
    int* gCursor     = (int*)bump((size_t)NBMAX * 4);            // memset to 0
    int* bar         = (int*)bump((size_t)BAR_INTS * 4);         // memset to 0
    float* norm      = (float*)bump((size_t)N * 4);
    int2* rsdeg      = (int2*)bump((size_t)N * 8);
    unsigned* tmp    = (unsigned*)bump((size_t)NB * LCAP * 4);   // 12.85 MB
    int* csr         = (int*)bump((size_t)NB * LCAP * 4);        // 12.85 MB
    unsigned* featb  = (unsigned*)bump((size_t)N * 64 * 4);      // bf16x2 rows
    unsigned* h1b    = (unsigned*)bump((size_t)N * 64 * 4);
    unsigned* h2b    = (unsigned*)bump((size_t)N * 64 * 4);
    ushort* Wb       = (ushort*)bump((size_t)D * 384 * 2);
    (void)ws_size;

    // zero gCursor + barrier state (contiguous in ws); the dispatch boundary
    // after the memset publishes the zeros before fused runs.
    hipMemsetAsync(gCursor, 0, (size_t)NBMAX * 4 + 256 + (size_t)BAR_INTS * 4,
                   stream);

    int nbin = (E + CH - 1) / CH;                    // 391
    int npre = (N * 64 + TPB_F - 1) / TPB_F;         // 12500
    int nwcv = (D * 384 / 4 + TPB_F - 1) / TPB_F;    // 24
    int total1 = nbin + npre + nwcv;

    // grid sizing once: plain launch is deadlock-free iff grid <= capacity.
    // bpc from the occupancy API (host-side computation; capture-safe).
    static int s_grid = 0;   // 0 = uncomputed, -1 = fallback
    if (s_grid == 0) {
        int bpc = 0;
        if (hipOccupancyMaxActiveBlocksPerMultiprocessor(&bpc, fused_kernel,
                                                         TPB_F, 0) != hipSuccess ||
            bpc < 1) {
            s_grid = -1;
        } else {
            long g = (long)bpc * 256;                // 256 CUs on MI355X
            if (g > 1024) g = 1024;                  // 4 blk/CU cap (32 waves)
            g &= ~7L;                                // multiple of 8 groups
            s_grid = (g >= 8) ? (int)g : -1;
        }
    }

    if (s_grid > 0) {
        int nbg = s_grid >> 3;                       // blocks per arrival group
        fused_kernel<<<s_grid, TPB_F, 0, stream>>>(
            src, dst, gCursor, bar, tmp, feat, featb, W, Wb,
            rsdeg, norm, csr, h1b, h2b,
            E, N, nbin, npre, total1, NB, nbg);
    } else {
        // 5-dispatch fallback pipeline
        mega_kernel<<<total1, TPB_F, 0, stream>>>(
            src, dst, gCursor, tmp, feat, featb, W, Wb, E, N, nbin, npre);
        bucket_csr_kernel<<<NB, TPB_F, 0, stream>>>(tmp, gCursor, rsdeg, norm, csr, N);
        const int spmm_blocks = (N * 64 + TPB - 1) / TPB;
        spmm_kernel<<<spmm_blocks, TPB, 0, stream>>>(
            (const uint4*)featb, rsdeg, csr, norm, h1b, N);
        spmm_kernel<<<spmm_blocks, TPB, 0, stream>>>(
            (const uint4*)h1b, rsdeg, csr, norm, h2b, N);
    }

    const int ntiles = (N + 15) / 16;                // 6250
    gemm_mfma_kernel<<<GEMM_GRID, TPB, 0, stream>>>(
        (const ushort*)featb, (const ushort*)h1b, (const ushort*)h2b,
        Wb, bias, out, N, ntiles);
}

// Round 8
// 364.462 us; speedup vs baseline: 1.9068x; 1.0031x over previous
//
#include <hip/hip_runtime.h>
#include <hip/hip_bf16.h>

// TAGConv K=2, D=128. Round 15.
// r7 decomposition: total(365.6) - fused(189.5) = 176us = gemm+memset+3gaps,
// while rounds 2-4 (same 176-183us residual) contained mega+csr+gemm+memset
// +6gaps -> gemm regressed ~30 -> ~140us. Only gemm change since r4:
// __builtin_nontemporal_store on C (r5) - NT bypasses L2 write-coalescing,
// 4 scattered 64B segments/wave go to HBM as partial-line RMW. REVERT to
// plain stores. Everything else identical to r7 (fused plain-launch kernel
// validated at 189.5us: mega+csr+2xspmm+3 xbar barriers).
// Pipeline: memset(2.8KB) -> fused(plain, 3 xbar) -> gemm.

#define D 128
#define TPB 256              // fallback spmm / gemm block
#define TPB_F 512            // fused kernel block (8 waves)
#define GEMM_GRID 768

#define BSH 9
#define BSZ 512              // nodes per bucket
#define NBMAX 256            // max buckets
#define EPT 8                // edges per thread in binscatter
#define CH (TPB_F * EPT)     // 4096 edges per chunk
#define LCAP 16384           // fixed per-bucket region (avg fill ~8.2K)

// barrier state layout (ints; one 128B line per counter)
#define XB_ACNT 0            // 8 group arrival lines: [g*32]
#define XB_ROOT (8 * 32)
#define XB_REL1 (9 * 32)
#define XB_CLAIM (10 * 32)   // 8 per-XCD claim lines: [10*32 + xcd*32]
#define XB_WDONE (18 * 32)
#define XB_REL2 (19 * 32)
#define BAR_INTS (20 * 32)

typedef __attribute__((ext_vector_type(8))) short short8;
typedef __attribute__((ext_vector_type(4))) float f32x4;

__device__ __forceinline__ ushort f2bf(float f) {
    unsigned u = __float_as_uint(f);
    u += 0x7fff + ((u >> 16) & 1);      // round-to-nearest-even
    return (ushort)(u >> 16);
}
__device__ __forceinline__ unsigned pack2bf(float x, float y) {
    return (unsigned)f2bf(x) | ((unsigned)f2bf(y) << 16);
}
__device__ __forceinline__ float bf_lo(unsigned v) { return __uint_as_float(v << 16); }
__device__ __forceinline__ float bf_hi(unsigned v) { return __uint_as_float(v & 0xffff0000u); }

// ---------------- grid barrier, XCD-level fencing (r6/r7-proven) ----------
// All counters monotonic (zeroed once per launch by host memset; barrier k
// uses threshold (k+1)*count). bar lines are ONLY ever accessed by atomics
// -> never L2-resident -> relaxed polls read LLC fresh, no cache-op per
// poll. After global arrival, ONE CAS-winner per XCD runs __threadfence()
// (wbl2+inv for its XCD: 8 walks/barrier instead of 2048); REL2 releases
// everyone only after all 8 XCDs flushed+invalidated. Spin caps: a missing
// release degrades to wrong results (visible) instead of a hang.
__device__ __forceinline__ void xbar(int* bar, int k, int nbg) {
    __syncthreads();
    if (threadIdx.x == 0) {
        int grp = (int)(blockIdx.x & 7);
        int a = atomicAdd(&bar[XB_ACNT + grp * 32], 1);
        if (a == nbg * (k + 1) - 1) {                 // last of my group
            int r = atomicAdd(&bar[XB_ROOT], 1);
            if (r == 8 * (k + 1) - 1)                 // last group overall
                atomicExch(&bar[XB_REL1], k + 1);
        }
        for (long it = 0;
             __hip_atomic_load(&bar[XB_REL1], __ATOMIC_RELAXED,
                               __HIP_MEMORY_SCOPE_AGENT) < k + 1; ++it) {
            __builtin_amdgcn_s_sleep(8);
            if (it > (1L << 22)) break;               // ~>100ms safety valve
        }
        int xcd;
        asm volatile("s_getreg_b32 %0, hwreg(HW_REG_XCC_ID)" : "=s"(xcd));
        xcd &= 7;
        if (atomicCAS(&bar[XB_CLAIM + xcd * 32], k, k + 1) == k) {
            __threadfence();                          // ONE wbl2+inv per XCD
            int d = atomicAdd(&bar[XB_WDONE], 1);
            if (d == 8 * (k + 1) - 1)
                atomicExch(&bar[XB_REL2], k + 1);
        }
        for (long it = 0;
             __hip_atomic_load(&bar[XB_REL2], __ATOMIC_RELAXED,
                               __HIP_MEMORY_SCOPE_AGENT) < k + 1; ++it) {
            __builtin_amdgcn_s_sleep(8);
            if (it > (1L << 22)) break;               // safety valve
        }
    }
    __syncthreads();
}

// ---------------- phase bodies (512-thread versions, r5/r6/r7-proven) -----

__device__ __forceinline__ void mega_body(
    int bid, int t,
    const int* __restrict__ src, const int* __restrict__ dst,
    int* __restrict__ gCursor, unsigned* __restrict__ tmp,
    const float* __restrict__ feat, unsigned* __restrict__ featb,
    const float* __restrict__ W, ushort* __restrict__ Wb,
    int e, int n, int nbin, int npre) {
    __shared__ int hist[NBMAX];
    __shared__ int cellBase[NBMAX];
    if (bid < nbin) {
        if (t < NBMAX) hist[t] = 0;
        __syncthreads();
        int base = bid * CH;
        int b[EPT]; unsigned pk[EPT]; int r[EPT];
#pragma unroll
        for (int k = 0; k < EPT; ++k) {
            int i = base + k * TPB_F + t;
            b[k] = -1;
            if (i < e) {
                int d = dst[i];
                b[k] = d >> BSH;
                pk[k] = ((unsigned)src[i] << BSH) | (unsigned)(d & (BSZ - 1));
                r[k] = atomicAdd(&hist[b[k]], 1);
            }
        }
        __syncthreads();
        if (t < NBMAX) {
            int h = hist[t];
            cellBase[t] = h ? t * LCAP + atomicAdd(&gCursor[t], h) : 0;
        }
        __syncthreads();
#pragma unroll
        for (int k = 0; k < EPT; ++k)
            if (b[k] >= 0) tmp[cellBase[b[k]] + r[k]] = pk[k];
        __syncthreads();            // LDS reuse guard (grid-stride loop)
    } else if (bid < nbin + npre) {
        int gid = (bid - nbin) * TPB_F + t;
        int node = gid >> 6, c = gid & 63;
        if (node < n) {
            float2 f = ((const float2*)(feat + (size_t)node * D))[c];
            featb[(size_t)node * 64 + c] = pack2bf(f.x, f.y);
        }
    } else {
        int i = ((bid - nbin - npre) * TPB_F + t) * 4;   // D*384 = 49152 elems
        float4 w = *(const float4*)(W + i);
        ushort4 o;
        o.x = f2bf(w.x); o.y = f2bf(w.y); o.z = f2bf(w.z); o.w = f2bf(w.w);
        *(ushort4*)(Wb + i) = o;
    }
}

__device__ __forceinline__ void bucket_body(
    int bkt, int t,
    const unsigned* __restrict__ tmp, const int* __restrict__ gCursor,
    int2* __restrict__ rsdeg, float* __restrict__ norm, int* __restrict__ csr,
    int n) {
    __shared__ int cnt[BSZ];
    __shared__ int off[BSZ];
    __shared__ int pr[BSZ];
    int beg = bkt * LCAP;
    int m = gCursor[bkt];
    int end = beg + m;
    cnt[t] = 0;
    __syncthreads();
    for (int i = beg + t; i < end; i += TPB_F)
        atomicAdd(&cnt[tmp[i] & (BSZ - 1)], 1);
    __syncthreads();
    int own = cnt[t];
    pr[t] = own;
    __syncthreads();
    for (int o = 1; o < BSZ; o <<= 1) {
        int x = (t >= o) ? pr[t - o] : 0;
        __syncthreads();
        pr[t] += x;
        __syncthreads();
    }
    off[t] = pr[t] - own;
    __syncthreads();
    cnt[t] = 0;                            // reuse as rank counters
    __syncthreads();
    for (int i = beg + t; i < end; i += TPB_F) {
        unsigned v = tmp[i];
        int l = v & (BSZ - 1);
        int r = atomicAdd(&cnt[l], 1);
        int idx = off[l] + r;
        if (idx < LCAP) csr[beg + idx] = (int)(v >> BSH);
    }
    __syncthreads();
    int node0 = bkt << BSH;
    {
        int node = node0 + t;
        if (node < n) {
            rsdeg[node] = make_int2(beg + off[t], cnt[t]);
            norm[node] = rsqrtf((float)cnt[t]);
        }
    }
    __syncthreads();                       // LDS reuse guard
}

__device__ __forceinline__ void spmm_body(
    const uint4* __restrict__ hin4, const int2* __restrict__ rsdeg,
    const int* __restrict__ csr, const float* __restrict__ norm,
    unsigned* __restrict__ hout, int n, int tpb) {
    int gw = (int)((blockIdx.x * tpb + threadIdx.x) >> 6);
    int nw = (int)((gridDim.x * tpb) >> 6);
    int lane = threadIdx.x & 63;
    int q = lane >> 4;
    int c = lane & 15;
    for (int w = gw; w < n; w += nw) {
        int2 rd = rsdeg[w];
        int beg = rd.x, end = rd.x + rd.y;
        float acc[8] = {};
#pragma unroll 4
        for (int j = beg + q; j < end; j += 4) {
            int u = csr[j];
            float s = norm[u];
            uint4 v = hin4[(u << 4) + c];
            acc[0] = fmaf(s, bf_lo(v.x), acc[0]);
            acc[1] = fmaf(s, bf_hi(v.x), acc[1]);
            acc[2] = fmaf(s, bf_lo(v.y), acc[2]);
            acc[3] = fmaf(s, bf_hi(v.y), acc[3]);
            acc[4] = fmaf(s, bf_lo(v.z), acc[4]);
            acc[5] = fmaf(s, bf_hi(v.z), acc[5]);
            acc[6] = fmaf(s, bf_lo(v.w), acc[6]);
            acc[7] = fmaf(s, bf_hi(v.w), acc[7]);
        }
#pragma unroll
        for (int k = 0; k < 8; ++k) {
            acc[k] += __shfl_xor(acc[k], 16, 64);
            acc[k] += __shfl_xor(acc[k], 32, 64);
        }
        if (q == 0) {
            float nv = norm[w];
            uint4 r;
            r.x = pack2bf(acc[0] * nv, acc[1] * nv);
            r.y = pack2bf(acc[2] * nv, acc[3] * nv);
            r.z = pack2bf(acc[4] * nv, acc[5] * nv);
            r.w = pack2bf(acc[6] * nv, acc[7] * nv);
            *(uint4*)(hout + (size_t)w * 64 + c * 4) = r;
        }
    }
}

// ---------------- fused kernel (plain launch, grid <= capacity) -----------
__global__ __launch_bounds__(TPB_F, 8) void fused_kernel(
    const int* __restrict__ src, const int* __restrict__ dst,
    int* __restrict__ gCursor, int* __restrict__ bar, unsigned* __restrict__ tmp,
    const float* __restrict__ feat, unsigned* __restrict__ featb,
    const float* __restrict__ W, ushort* __restrict__ Wb,
    int2* __restrict__ rsdeg, float* __restrict__ norm, int* __restrict__ csr,
    unsigned* __restrict__ h1b, unsigned* __restrict__ h2b,
    int e, int n, int nbin, int npre, int total1, int nb, int nbg) {
    int t = threadIdx.x;

    // phase 1: binscatter || prescale || wconv (gCursor pre-zeroed by memset)
    for (int bid = blockIdx.x; bid < total1; bid += gridDim.x)
        mega_body(bid, t, src, dst, gCursor, tmp, feat, featb, W, Wb,
                  e, n, nbin, npre);
    xbar(bar, 0, nbg);

    // phase 2: per-bucket CSR
    for (int bkt = blockIdx.x; bkt < nb; bkt += gridDim.x)
        bucket_body(bkt, t, tmp, gCursor, rsdeg, norm, csr, n);
    xbar(bar, 1, nbg);

    // phase 3: hop 1
    spmm_body((const uint4*)featb, rsdeg, csr, norm, h1b, n, TPB_F);
    xbar(bar, 2, nbg);

    // phase 4: hop 2
    spmm_body((const uint4*)h1b, rsdeg, csr, norm, h2b, n, TPB_F);
}

// ---------------- fallback wrappers (non-fused path) ----------------
__global__ __launch_bounds__(TPB_F) void mega_kernel(
    const int* __restrict__ src, const int* __restrict__ dst,
    int* __restrict__ gCursor, unsigned* __restrict__ tmp,
    const float* __restrict__ feat, unsigned* __restrict__ featb,
    const float* __restrict__ W, ushort* __restrict__ Wb,
    int e, int n, int nbin, int npre) {
    mega_body(blockIdx.x, threadIdx.x, src, dst, gCursor, tmp, feat, featb,
              W, Wb, e, n, nbin, npre);
}

__global__ __launch_bounds__(TPB_F) void bucket_csr_kernel(
    const unsigned* __restrict__ tmp, const int* __restrict__ gCursor,
    int2* __restrict__ rsdeg, float* __restrict__ norm, int* __restrict__ csr,
    int n) {
    bucket_body(blockIdx.x, threadIdx.x, tmp, gCursor, rsdeg, norm, csr, n);
}

__global__ __launch_bounds__(TPB, 8) void spmm_kernel(
    const uint4* __restrict__ hin4, const int2* __restrict__ rsdeg,
    const int* __restrict__ csr, const float* __restrict__ norm,
    unsigned* __restrict__ hout, int n) {
    spmm_body(hin4, rsdeg, csr, norm, hout, n, TPB);
}

// ---------------- GEMM: out[n][128] = [featb|h1b|h2b] @ Wb^T + b -----------
// 4 waves/block; wave owns a 32-col W slice in registers (24 bf16 frags).
// A frag: row m=lane&15, k=(lane>>4)*8+j.  C/D: col=lane&15, row=(lane>>4)*4+reg.
// r15: PLAIN C stores (r5's nontemporal stores bypassed L2 write-coalescing
// -> partial-line HBM RMW -> gemm ~30 -> ~140us; reverted).
__global__ __launch_bounds__(TPB) void gemm_mfma_kernel(
    const ushort* __restrict__ featb, const ushort* __restrict__ h1b,
    const ushort* __restrict__ h2b, const ushort* __restrict__ Wb,
    const float* __restrict__ bias, float* __restrict__ out, int n, int ntiles) {
    int lane = threadIdx.x & 63;
    int wave = threadIdx.x >> 6;
    int m = lane & 15, q = lane >> 4;

    short8 b[12][2];
#pragma unroll
    for (int ks = 0; ks < 12; ++ks)
#pragma unroll
        for (int t = 0; t < 2; ++t)
            b[ks][t] = *(const short8*)(Wb + (size_t)(wave * 32 + t * 16 + m) * 384
                                        + ks * 32 + q * 8);
    float bv0 = bias[wave * 32 + m];
    float bv1 = bias[wave * 32 + 16 + m];

    const ushort* srcs[3] = {featb, h1b, h2b};

    for (int tile = blockIdx.x; tile < ntiles; tile += gridDim.x) {
        int row = tile * 16 + m;
        bool va = row < n;
        size_t arow = (size_t)row * D;
        short8 a[12] = {};
        if (va) {
#pragma unroll
            for (int ks = 0; ks < 12; ++ks)
                a[ks] = *(const short8*)(srcs[ks >> 2] + arow + (ks & 3) * 32 + q * 8);
        }
        f32x4 acc0 = {}, acc1 = {};
#pragma unroll
        for (int ks = 0; ks < 12; ++ks) {
            acc0 = __builtin_amdgcn_mfma_f32_16x16x32_bf16(a[ks], b[ks][0], acc0, 0, 0, 0);
            acc1 = __builtin_amdgcn_mfma_f32_16x16x32_bf16(a[ks], b[ks][1], acc1, 0, 0, 0);
        }
        int r0 = tile * 16 + q * 4;
#pragma unroll
        for (int r = 0; r < 4; ++r) {
            int rw = r0 + r;
            if (rw < n) {
                size_t o = (size_t)rw * D + wave * 32 + m;
                out[o] = acc0[r] + bv0;
                out[o + 16] = acc1[r] + bv1;
            }
        }
    }
}

extern "C" void kernel_launch(void* const* d_in, const int* in_sizes, int n_in,
                              void* d_out, int out_size, void* d_ws, size_t ws_size,
                              hipStream_t stream) {
    const float* feat = (const float*)d_in[0];
    const int* src    = (const int*)d_in[1];
    const int* dst    = (const int*)d_in[2];
    const float* W    = (const float*)d_in[3];
    const float* bias = (const float*)d_in[4];
    float* out        = (float*)d_out;

    int N = in_sizes[0] / D;        // 100000
    int E = in_sizes[1];            // 1600000
    int NB = (N + BSZ - 1) >> BSH;  // 196

    char* ws = (char*)d_ws;
    size_t off = 0;
    auto bump = [&](size_t bytes) {
        char* p = ws + off;
        off += (bytes + 255) & ~(size_t)255;
        return p;
    };
    int* gCursor     = (int*)bump((size_t)NBMAX * 4);            // memset to 0
    int* bar         = (int*)bump((size_t)BAR_INTS * 4);         // memset to 0
    float* norm      = (float*)bump((size_t)N * 4);
    int2* rsdeg      = (int2*)bump((size_t)N * 8);
    unsigned* tmp    = (unsigned*)bump((size_t)NB * LCAP * 4);   // 12.85 MB
    int* csr         = (int*)bump((size_t)NB * LCAP * 4);        // 12.85 MB
    unsigned* featb  = (unsigned*)bump((size_t)N * 64 * 4);      // bf16x2 rows
    unsigned* h1b    = (unsigned*)bump((size_t)N * 64 * 4);
    unsigned* h2b    = (unsigned*)bump((size_t)N * 64 * 4);
    ushort* Wb       = (ushort*)bump((size_t)D * 384 * 2);
    (void)ws_size;

    // zero gCursor + barrier state (contiguous in ws); the dispatch boundary
    // after the memset publishes the zeros before fused runs.
    hipMemsetAsync(gCursor, 0, (size_t)NBMAX * 4 + 256 + (size_t)BAR_INTS * 4,
                   stream);

    int nbin = (E + CH - 1) / CH;                    // 391
    int npre = (N * 64 + TPB_F - 1) / TPB_F;         // 12500
    int nwcv = (D * 384 / 4 + TPB_F - 1) / TPB_F;    // 24
    int total1 = nbin + npre + nwcv;

    // grid sizing once: plain launch is deadlock-free iff grid <= capacity.
    // bpc from the occupancy API (host-side computation; capture-safe).
    static int s_grid = 0;   // 0 = uncomputed, -1 = fallback
    if (s_grid == 0) {
        int bpc = 0;
        if (hipOccupancyMaxActiveBlocksPerMultiprocessor(&bpc, fused_kernel,
                                                         TPB_F, 0) != hipSuccess ||
            bpc < 1) {
            s_grid = -1;
        } else {
            long g = (long)bpc * 256;                // 256 CUs on MI355X
            if (g > 1024) g = 1024;                  // 4 blk/CU cap (32 waves)
            g &= ~7L;                                // multiple of 8 groups
            s_grid = (g >= 8) ? (int)g : -1;
        }
    }

    if (s_grid > 0) {
        int nbg = s_grid >> 3;                       // blocks per arrival group
        fused_kernel<<<s_grid, TPB_F, 0, stream>>>(
            src, dst, gCursor, bar, tmp, feat, featb, W, Wb,
            rsdeg, norm, csr, h1b, h2b,
            E, N, nbin, npre, total1, NB, nbg);
    } else {
        // 5-dispatch fallback pipeline
        mega_kernel<<<total1, TPB_F, 0, stream>>>(
            src, dst, gCursor, tmp, feat, featb, W, Wb, E, N, nbin, npre);
        bucket_csr_kernel<<<NB, TPB_F, 0, stream>>>(tmp, gCursor, rsdeg, norm, csr, N);
        const int spmm_blocks = (N * 64 + TPB - 1) / TPB;
        spmm_kernel<<<spmm_blocks, TPB, 0, stream>>>(
            (const uint4*)featb, rsdeg, csr, norm, h1b, N);
        spmm_kernel<<<spmm_blocks, TPB, 0, stream>>>(
            (const uint4*)h1b, rsdeg, csr, norm, h2b, N);
    }

    const int ntiles = (N + 15) / 16;                // 6250
    gemm_mfma_kernel<<<GEMM_GRID, TPB, 0, stream>>>(
        (const ushort*)featb, (const ushort*)h1b, (const ushort*)h2b,
        Wb, bias, out, N, ntiles);
}

// Round 9
// 301.310 us; speedup vs baseline: 2.3065x; 1.2096x over previous
//
#include <hip/hip_runtime.h>
#include <hip/hip_bf16.h>

// TAGConv K=2, D=128. Round 16: revert to the r4/round-11 structure — the
// measured session best (301.4us).
// Session evidence log:
//  - spmm floor: 62.9us/hop = 183MB random 256B gathers at ~2.9TB/s
//    miss-path; MLP is ample (22 waves/CU x ~2 gathers in flight); three
//    source-level restructures (packed asm, manual pipeline, launch-bounds
//    VGPR raise) all confirmed the compiler/HW ceiling. Do not touch.
//  - Fusion arc (r1,r5,r6,r7,r8): fused{mega,csr,spmm1,spmm2} with xbar
//    barrier = 190us under rocprof replay BUT the bench totals show ~60-90us
//    of extra cost under graph execution (barriers ~30us each there, vs ~8
//    in replay; same-line LLC atomic serialization + release propagation).
//    Grid-wide sync costs more than the ~13-17us dispatch gaps it replaces
//    on this chip/harness. CLOSED — do not retry, including partial fusion.
//  - NT stores on gemm C: neutral (r7->r8 delta 1.1us). gemm < 62.9us
//    (never in top-5 of 6-dispatch rounds).
// Pipeline: memset(1KB) -> mega -> bucket_csr(512t) -> spmm1 -> spmm2 -> gemm.

#define D 128
#define TPB 256
#define CSR_TPB 512
#define GEMM_GRID 768

#define BSH 9
#define BSZ 512              // nodes per bucket
#define NBMAX 256            // max buckets
#define EPT 16               // edges per thread in binscatter
#define CH (TPB * EPT)       // 4096 edges per WG
#define LCAP 16384           // fixed per-bucket region (avg fill ~8.2K, ~90 sigma)

typedef __attribute__((ext_vector_type(8))) short short8;
typedef __attribute__((ext_vector_type(4))) float f32x4;

__device__ __forceinline__ ushort f2bf(float f) {
    unsigned u = __float_as_uint(f);
    u += 0x7fff + ((u >> 16) & 1);      // round-to-nearest-even
    return (ushort)(u >> 16);
}
__device__ __forceinline__ unsigned pack2bf(float x, float y) {
    return (unsigned)f2bf(x) | ((unsigned)f2bf(y) << 16);
}
__device__ __forceinline__ float bf_lo(unsigned v) { return __uint_as_float(v << 16); }
__device__ __forceinline__ float bf_hi(unsigned v) { return __uint_as_float(v & 0xffff0000u); }

// ---------------- mega: binscatter || prescale || wconv ----------------
// blocks [0, nbin): bin edges into fixed bucket regions (packed 4B:
//   pk = (src<<9)|(dst&511)); one global atomic per (WG,bucket).
// blocks [nbin, nbin+npre): featb = bf16(feat).
// blocks [nbin+npre, ...): Wb = bf16(W).
__global__ __launch_bounds__(TPB) void mega_kernel(
    const int* __restrict__ src, const int* __restrict__ dst,
    int* __restrict__ gCursor, unsigned* __restrict__ tmp,
    const float* __restrict__ feat, unsigned* __restrict__ featb,
    const float* __restrict__ W, ushort* __restrict__ Wb,
    int e, int n, int nbin, int npre) {
    __shared__ int hist[NBMAX];
    __shared__ int cellBase[NBMAX];
    int t = threadIdx.x;
    int bid = blockIdx.x;

    if (bid < nbin) {
        hist[t] = 0;
        __syncthreads();
        int base = bid * CH;
        int b[EPT]; unsigned pk[EPT]; int r[EPT];
#pragma unroll
        for (int k = 0; k < EPT; ++k) {
            int i = base + k * TPB + t;
            b[k] = -1;
            if (i < e) {
                int d = dst[i];
                b[k] = d >> BSH;
                pk[k] = ((unsigned)src[i] << BSH) | (unsigned)(d & (BSZ - 1));
                r[k] = atomicAdd(&hist[b[k]], 1);
            }
        }
        __syncthreads();
        int h = hist[t];
        cellBase[t] = h ? t * LCAP + atomicAdd(&gCursor[t], h) : 0;
        __syncthreads();
#pragma unroll
        for (int k = 0; k < EPT; ++k)
            if (b[k] >= 0) tmp[cellBase[b[k]] + r[k]] = pk[k];
    } else if (bid < nbin + npre) {
        int gid = (bid - nbin) * TPB + t;
        int node = gid >> 6, c = gid & 63;
        if (node >= n) return;
        float2 f = ((const float2*)(feat + (size_t)node * D))[c];
        featb[(size_t)node * 64 + c] = pack2bf(f.x, f.y);
    } else {
        int i = ((bid - nbin - npre) * TPB + t) * 4;   // D*384 = 49152 elems
        float4 w = *(const float4*)(W + i);
        ushort4 o;
        o.x = f2bf(w.x); o.y = f2bf(w.y); o.z = f2bf(w.z); o.w = f2bf(w.w);
        *(ushort4*)(Wb + i) = o;
    }
}

// ---------------- per-bucket CSR in LDS + sequential dump ----------
// One WG per bucket, CSR_TPB=512 threads (== BSZ). Emits csr slice
// (coalesced, at bkt*LCAP), rsdeg, norm.
__global__ __launch_bounds__(CSR_TPB) void bucket_csr_kernel(
    const unsigned* __restrict__ tmp, const int* __restrict__ gCursor,
    int2* __restrict__ rsdeg, float* __restrict__ norm, int* __restrict__ csr,
    int n) {
    __shared__ int cnt[BSZ];
    __shared__ int off[BSZ];
    __shared__ int pr[BSZ];
    __shared__ int lcsr[LCAP];
    int t = threadIdx.x;
    int bkt = blockIdx.x;
    int beg = bkt * LCAP;
    int m = gCursor[bkt];
    int end = beg + m;
    cnt[t] = 0;
    __syncthreads();
    for (int i = beg + t; i < end; i += CSR_TPB)
        atomicAdd(&cnt[tmp[i] & (BSZ - 1)], 1);
    __syncthreads();
    // exclusive scan of cnt[512] via 512-thread Hillis-Steele
    int own = cnt[t];
    pr[t] = own;
    __syncthreads();
    for (int o = 1; o < BSZ; o <<= 1) {
        int x = (t >= o) ? pr[t - o] : 0;
        __syncthreads();
        pr[t] += x;
        __syncthreads();
    }
    off[t] = pr[t] - own;
    __syncthreads();
    cnt[t] = 0;                            // reuse as rank counters
    __syncthreads();
    for (int i = beg + t; i < end; i += CSR_TPB) {
        unsigned v = tmp[i];
        int l = v & (BSZ - 1);
        int r = atomicAdd(&cnt[l], 1);
        int idx = off[l] + r;
        if (idx < LCAP) lcsr[idx] = (int)(v >> BSH);
    }
    __syncthreads();
    int mm = m < LCAP ? m : LCAP;
    for (int i = t; i < mm; i += CSR_TPB) csr[beg + i] = lcsr[i];   // sequential
    int node0 = bkt << BSH;
    {
        int node = node0 + t;
        if (node < n) {
            rsdeg[node] = make_int2(beg + off[t], cnt[t]);
            norm[node] = rsqrtf((float)cnt[t]);
        }
    }
}

// ---------------- SpMM: hout[v] = bf16( norm[v] * sum_u norm[u]*hin[u] ) ----
// One wave per dst node; quarter-wave q handles edge beg+j*4+q; c = lane&15
// handles a 16B column chunk. 1 KB per gather instruction; unroll 4.
// __launch_bounds__(TPB,8): VGPR cap 64 at full occupancy (measured best).
__global__ __launch_bounds__(TPB, 8) void spmm_kernel(
    const uint4* __restrict__ hin4, const int2* __restrict__ rsdeg,
    const int* __restrict__ csr, const float* __restrict__ norm,
    unsigned* __restrict__ hout, int n) {
    int w = (blockIdx.x * TPB + threadIdx.x) >> 6;
    if (w >= n) return;
    int lane = threadIdx.x & 63;
    int q = lane >> 4;
    int c = lane & 15;
    int2 rd = rsdeg[w];
    int beg = rd.x, end = rd.x + rd.y;
    float acc[8] = {};
#pragma unroll 4
    for (int j = beg + q; j < end; j += 4) {
        int u = csr[j];
        float s = norm[u];
        uint4 v = hin4[(u << 4) + c];
        acc[0] = fmaf(s, bf_lo(v.x), acc[0]);
        acc[1] = fmaf(s, bf_hi(v.x), acc[1]);
        acc[2] = fmaf(s, bf_lo(v.y), acc[2]);
        acc[3] = fmaf(s, bf_hi(v.y), acc[3]);
        acc[4] = fmaf(s, bf_lo(v.z), acc[4]);
        acc[5] = fmaf(s, bf_hi(v.z), acc[5]);
        acc[6] = fmaf(s, bf_lo(v.w), acc[6]);
        acc[7] = fmaf(s, bf_hi(v.w), acc[7]);
    }
#pragma unroll
    for (int k = 0; k < 8; ++k) {
        acc[k] += __shfl_xor(acc[k], 16, 64);
        acc[k] += __shfl_xor(acc[k], 32, 64);
    }
    if (q == 0) {
        float nv = norm[w];
        uint4 r;
        r.x = pack2bf(acc[0] * nv, acc[1] * nv);
        r.y = pack2bf(acc[2] * nv, acc[3] * nv);
        r.z = pack2bf(acc[4] * nv, acc[5] * nv);
        r.w = pack2bf(acc[6] * nv, acc[7] * nv);
        *(uint4*)(hout + (size_t)w * 64 + c * 4) = r;
    }
}

// ---------------- GEMM: out[n][128] = [featb|h1b|h2b] @ Wb^T + b ----------------
// 4 waves/block; wave owns a 32-col W slice in registers (24 bf16 frags).
// A frag: row m=lane&15, k=(lane>>4)*8+j.  C/D: col=lane&15, row=(lane>>4)*4+reg.
// Plain C stores (NT stores measured neutral; keep simple).
__global__ __launch_bounds__(TPB) void gemm_mfma_kernel(
    const ushort* __restrict__ featb, const ushort* __restrict__ h1b,
    const ushort* __restrict__ h2b, const ushort* __restrict__ Wb,
    const float* __restrict__ bias, float* __restrict__ out, int n, int ntiles) {
    int lane = threadIdx.x & 63;
    int wave = threadIdx.x >> 6;
    int m = lane & 15, q = lane >> 4;

    short8 b[12][2];
#pragma unroll
    for (int ks = 0; ks < 12; ++ks)
#pragma unroll
        for (int t = 0; t < 2; ++t)
            b[ks][t] = *(const short8*)(Wb + (size_t)(wave * 32 + t * 16 + m) * 384
                                        + ks * 32 + q * 8);
    float bv0 = bias[wave * 32 + m];
    float bv1 = bias[wave * 32 + 16 + m];

    const ushort* srcs[3] = {featb, h1b, h2b};

    for (int tile = blockIdx.x; tile < ntiles; tile += gridDim.x) {
        int row = tile * 16 + m;
        bool va = row < n;
        size_t arow = (size_t)row * D;
        short8 a[12] = {};
        if (va) {
#pragma unroll
            for (int ks = 0; ks < 12; ++ks)
                a[ks] = *(const short8*)(srcs[ks >> 2] + arow + (ks & 3) * 32 + q * 8);
        }
        f32x4 acc0 = {}, acc1 = {};
#pragma unroll
        for (int ks = 0; ks < 12; ++ks) {
            acc0 = __builtin_amdgcn_mfma_f32_16x16x32_bf16(a[ks], b[ks][0], acc0, 0, 0, 0);
            acc1 = __builtin_amdgcn_mfma_f32_16x16x32_bf16(a[ks], b[ks][1], acc1, 0, 0, 0);
        }
        int r0 = tile * 16 + q * 4;
#pragma unroll
        for (int r = 0; r < 4; ++r) {
            int rw = r0 + r;
            if (rw < n) {
                size_t o = (size_t)rw * D + wave * 32 + m;
                out[o] = acc0[r] + bv0;
                out[o + 16] = acc1[r] + bv1;
            }
        }
    }
}

extern "C" void kernel_launch(void* const* d_in, const int* in_sizes, int n_in,
                              void* d_out, int out_size, void* d_ws, size_t ws_size,
                              hipStream_t stream) {
    const float* feat = (const float*)d_in[0];
    const int* src    = (const int*)d_in[1];
    const int* dst    = (const int*)d_in[2];
    const float* W    = (const float*)d_in[3];
    const float* bias = (const float*)d_in[4];
    float* out        = (float*)d_out;

    const int N = in_sizes[0] / D;        // 100000
    const int E = in_sizes[1];            // 1600000
    const int NB = (N + BSZ - 1) >> BSH;  // 196

    char* ws = (char*)d_ws;
    size_t off = 0;
    auto bump = [&](size_t bytes) {
        char* p = ws + off;
        off += (bytes + 255) & ~(size_t)255;
        return p;
    };
    int* gCursor     = (int*)bump((size_t)NBMAX * 4);            // memset to 0
    float* norm      = (float*)bump((size_t)N * 4);
    int2* rsdeg      = (int2*)bump((size_t)N * 8);
    unsigned* tmp    = (unsigned*)bump((size_t)NB * LCAP * 4);   // 12.85 MB
    int* csr         = (int*)bump((size_t)NB * LCAP * 4);        // 12.85 MB
    unsigned* featb  = (unsigned*)bump((size_t)N * 64 * 4);      // bf16x2 rows
    unsigned* h1b    = (unsigned*)bump((size_t)N * 64 * 4);
    unsigned* h2b    = (unsigned*)bump((size_t)N * 64 * 4);
    ushort* Wb       = (ushort*)bump((size_t)D * 384 * 2);
    (void)ws_size;

    hipMemsetAsync(gCursor, 0, (size_t)NBMAX * 4, stream);

    const int nbin = (E + CH - 1) / CH;                // 391
    const int npre = (N * 64 + TPB - 1) / TPB;         // 25000
    const int nwcv = (D * 384 / 4 + TPB - 1) / TPB;    // 48
    mega_kernel<<<nbin + npre + nwcv, TPB, 0, stream>>>(
        src, dst, gCursor, tmp, feat, featb, W, Wb, E, N, nbin, npre);

    bucket_csr_kernel<<<NB, CSR_TPB, 0, stream>>>(tmp, gCursor, rsdeg, norm, csr, N);

    const int spmm_blocks = (N * 64 + TPB - 1) / TPB;  // 1 wave per node
    spmm_kernel<<<spmm_blocks, TPB, 0, stream>>>((const uint4*)featb, rsdeg, csr, norm, h1b, N);
    spmm_kernel<<<spmm_blocks, TPB, 0, stream>>>((const uint4*)h1b, rsdeg, csr, norm, h2b, N);

    const int ntiles = (N + 15) / 16;                  // 6250
    gemm_mfma_kernel<<<GEMM_GRID, TPB, 0, stream>>>(
        (const ushort*)featb, (const ushort*)h1b, (const ushort*)h2b,
        Wb, bias, out, N, ntiles);
}